// Round 1
// baseline (423.162 us; speedup 1.0000x reference)
//
#include <hip/hip_runtime.h>

// Sinkhorn iteration factored as C = diag(u) * C0 * diag(v).
// One wave (64 lanes) per node. Lane L owns a 16x4 subtile:
//   rows {4t + (L>>4)}, t=0..15 ; cols {4*(L&15)+k}, k=0..3
// which is exactly the ownership induced by float4 loads:
//   load t: float4 at flat index 256*t + 4*L  -> row 4t+(L>>4), col 4*(L&15)..+3
//
// Per iteration:
//   v_j = 1 / sum_i u_i C0[i,j]  : 64 FMA lane-local + fold over row-groups (xor 16,32)
//   u_i = 1 / sum_j C0[i,j] v_j  : 64 FMA lane-local + fold over col-groups (xor 1,2,4,8)
// Final: out[i,j] = u_i * C0[i,j] * v_j.

__global__ __launch_bounds__(256) void sinkhorn_kernel(
    const float* __restrict__ M, float* __restrict__ out, int num_node) {

    const int wavesPerBlock = blockDim.x >> 6;
    const int node = blockIdx.x * wavesPerBlock + (threadIdx.x >> 6);
    if (node >= num_node) return;
    const int lane = threadIdx.x & 63;

    const float* __restrict__ Mn = M + (size_t)node * 4096;
    float* __restrict__ On = out + (size_t)node * 4096;

    // ---- load 64x64 tile, float4 per instruction, fully coalesced ----
    float c[16][4];
    #pragma unroll
    for (int t = 0; t < 16; ++t) {
        const float4 val = *reinterpret_cast<const float4*>(Mn + 256 * t + 4 * lane);
        c[t][0] = val.x; c[t][1] = val.y; c[t][2] = val.z; c[t][3] = val.w;
    }

    // ---- C0 = exp(sigmoid(clamp(M,-10,10)) / 0.01) ----
    #pragma unroll
    for (int t = 0; t < 16; ++t) {
        #pragma unroll
        for (int k = 0; k < 4; ++k) {
            float x = c[t][k];
            x = fminf(10.0f, fmaxf(-10.0f, x));
            float s = 1.0f / (1.0f + expf(-x));
            c[t][k] = expf(s * 100.0f);
        }
    }

    // ---- Sinkhorn scaling vectors ----
    float u[16];
    #pragma unroll
    for (int t = 0; t < 16; ++t) u[t] = 1.0f;
    float v[4] = {1.0f, 1.0f, 1.0f, 1.0f};

    #pragma unroll
    for (int it = 0; it < 5; ++it) {
        // column sums: d_j = sum_i u_i * C0[i,j]
        float d[4];
        #pragma unroll
        for (int k = 0; k < 4; ++k) {
            float acc = 0.0f;
            #pragma unroll
            for (int t = 0; t < 16; ++t) acc = fmaf(u[t], c[t][k], acc);
            d[k] = acc;
        }
        // fold across the 4 row-groups (lanes differing in bits 4,5)
        #pragma unroll
        for (int k = 0; k < 4; ++k) {
            d[k] += __shfl_xor(d[k], 16, 64);
            d[k] += __shfl_xor(d[k], 32, 64);
            v[k] = 1.0f / d[k];
        }
        // row sums: e_i = sum_j C0[i,j] * v_j
        #pragma unroll
        for (int t = 0; t < 16; ++t) {
            float acc = 0.0f;
            #pragma unroll
            for (int k = 0; k < 4; ++k) acc = fmaf(c[t][k], v[k], acc);
            // fold across the 16 col-groups (lanes differing in bits 0..3)
            acc += __shfl_xor(acc, 1, 64);
            acc += __shfl_xor(acc, 2, 64);
            acc += __shfl_xor(acc, 4, 64);
            acc += __shfl_xor(acc, 8, 64);
            u[t] = 1.0f / acc;
        }
    }

    // ---- write out = u_i * C0[i,j] * v_j, coalesced float4 ----
    #pragma unroll
    for (int t = 0; t < 16; ++t) {
        float4 o;
        o.x = u[t] * c[t][0] * v[0];
        o.y = u[t] * c[t][1] * v[1];
        o.z = u[t] * c[t][2] * v[2];
        o.w = u[t] * c[t][3] * v[3];
        *reinterpret_cast<float4*>(On + 256 * t + 4 * lane) = o;
    }
}

extern "C" void kernel_launch(void* const* d_in, const int* in_sizes, int n_in,
                              void* d_out, int out_size, void* d_ws, size_t ws_size,
                              hipStream_t stream) {
    const float* M = (const float*)d_in[0];
    float* out = (float*)d_out;
    const int num_node = in_sizes[0] / 4096;   // 64*64 per node

    const int wavesPerBlock = 4;               // 256 threads
    const int blocks = (num_node + wavesPerBlock - 1) / wavesPerBlock;
    sinkhorn_kernel<<<blocks, 256, 0, stream>>>(M, out, num_node);
}

// Round 2
// 325.346 us; speedup vs baseline: 1.3007x; 1.3007x over previous
//
#include <hip/hip_runtime.h>

// Sinkhorn iteration factored as C = diag(u) * C0 * diag(v).
// One wave (64 lanes) per node. Lane L owns a 16x4 subtile:
//   rows {4t + (L>>4)}, t=0..15 ; cols {4*(L&15)+k}, k=0..3
// (ownership induced by coalesced float4 loads at flat index 256*t + 4*L).
//
// Per iteration:
//   v_j = 1 / sum_i u_i C0[i,j]  : lane-local FMA + fold over row-groups (xor 16,32)
//   u_i = 1 / sum_j C0[i,j] v_j  : lane-local FMA + fold over col-groups (xor 1,2,4,8)
// Final: out[i,j] = u_i * C0[i,j] * v_j.
//
// All transcendentals via HW instructions (v_exp_f32 / v_rcp_f32): ~1 ulp,
// absorbed by the normalization; threshold is 1.8e-2.

#define LOG2E 1.4426950408889634f

__device__ __forceinline__ float fast_rcp(float x) {
    return __builtin_amdgcn_rcpf(x);
}
__device__ __forceinline__ float fast_exp2(float x) {
    return __builtin_amdgcn_exp2f(x);
}

__global__ __launch_bounds__(256) void sinkhorn_kernel(
    const float* __restrict__ M, float* __restrict__ out, int num_node) {

    const int wavesPerBlock = blockDim.x >> 6;
    const int node = blockIdx.x * wavesPerBlock + (threadIdx.x >> 6);
    if (node >= num_node) return;
    const int lane = threadIdx.x & 63;

    const float* __restrict__ Mn = M + (size_t)node * 4096;
    float* __restrict__ On = out + (size_t)node * 4096;

    // ---- load 64x64 tile, float4 per instruction, fully coalesced ----
    float c[16][4];
    #pragma unroll
    for (int t = 0; t < 16; ++t) {
        const float4 val = *reinterpret_cast<const float4*>(Mn + 256 * t + 4 * lane);
        c[t][0] = val.x; c[t][1] = val.y; c[t][2] = val.z; c[t][3] = val.w;
    }

    // ---- C0 = exp(sigmoid(clamp(M,-10,10)) / 0.01) via v_exp_f32/v_rcp_f32 ----
    #pragma unroll
    for (int t = 0; t < 16; ++t) {
        #pragma unroll
        for (int k = 0; k < 4; ++k) {
            float x = c[t][k];
            x = fminf(10.0f, fmaxf(-10.0f, x));          // v_med3_f32
            float e = fast_exp2(-x * LOG2E);             // e^-x
            float s = fast_rcp(1.0f + e);                // sigmoid
            c[t][k] = fast_exp2(s * (100.0f * LOG2E));   // e^(s/gamma)
        }
    }

    // ---- Sinkhorn scaling vectors ----
    float u[16];
    #pragma unroll
    for (int t = 0; t < 16; ++t) u[t] = 1.0f;
    float v[4] = {1.0f, 1.0f, 1.0f, 1.0f};

    #pragma unroll
    for (int it = 0; it < 5; ++it) {
        // column sums: d_j = sum_i u_i * C0[i,j]
        float d[4];
        #pragma unroll
        for (int k = 0; k < 4; ++k) {
            float acc = 0.0f;
            #pragma unroll
            for (int t = 0; t < 16; ++t) acc = fmaf(u[t], c[t][k], acc);
            d[k] = acc;
        }
        // fold across the 4 row-groups (lanes differing in bits 4,5)
        #pragma unroll
        for (int k = 0; k < 4; ++k) {
            d[k] += __shfl_xor(d[k], 16, 64);
            d[k] += __shfl_xor(d[k], 32, 64);
            v[k] = fast_rcp(d[k]);
        }
        // row sums: e_i = sum_j C0[i,j] * v_j
        #pragma unroll
        for (int t = 0; t < 16; ++t) {
            float acc = 0.0f;
            #pragma unroll
            for (int k = 0; k < 4; ++k) acc = fmaf(c[t][k], v[k], acc);
            // fold across the 16 col-groups (lanes differing in bits 0..3)
            acc += __shfl_xor(acc, 1, 64);
            acc += __shfl_xor(acc, 2, 64);
            acc += __shfl_xor(acc, 4, 64);
            acc += __shfl_xor(acc, 8, 64);
            u[t] = fast_rcp(acc);
        }
    }

    // ---- write out = u_i * C0[i,j] * v_j, coalesced float4 ----
    #pragma unroll
    for (int t = 0; t < 16; ++t) {
        float4 o;
        o.x = u[t] * c[t][0] * v[0];
        o.y = u[t] * c[t][1] * v[1];
        o.z = u[t] * c[t][2] * v[2];
        o.w = u[t] * c[t][3] * v[3];
        *reinterpret_cast<float4*>(On + 256 * t + 4 * lane) = o;
    }
}

extern "C" void kernel_launch(void* const* d_in, const int* in_sizes, int n_in,
                              void* d_out, int out_size, void* d_ws, size_t ws_size,
                              hipStream_t stream) {
    const float* M = (const float*)d_in[0];
    float* out = (float*)d_out;
    const int num_node = in_sizes[0] / 4096;   // 64*64 per node

    const int wavesPerBlock = 4;               // 256 threads
    const int blocks = (num_node + wavesPerBlock - 1) / wavesPerBlock;
    sinkhorn_kernel<<<blocks, 256, 0, stream>>>(M, out, num_node);
}